// Round 14
// baseline (42.254 us; speedup 1.0000x reference)
//
#include <hip/hip_runtime.h>

#define DIM    1024
#define BATCH  8
#define QLEN   4096
#define SEQ    128

typedef float vfloat4 __attribute__((ext_vector_type(4)));

// ---------- Kernel A: vp partials, 1024 blocks ----------
// grid 1024 = m(2) x c(16 d-chunks of 64) x es(32 e-ranges of 32); 256 thr.
// vp[es][m,b,d] = sum_{e in es-range} h_last[b,e] * Wv[m,e,DIM+d]
// Weights read exactly once (nontemporal); all 8 batches in registers.
__global__ void __launch_bounds__(256) kernelA(const float* __restrict__ hidden,
                                               const float* __restrict__ c_attn_w,
                                               float* __restrict__ vp) {
    __shared__ float h_s[BATCH][32];
    __shared__ vfloat4 vred[16][16][9];   // [eg][d4][b] (padded)

    const int tid = threadIdx.x;
    const int es = blockIdx.x & 31;
    const int c  = (blockIdx.x >> 5) & 15;
    const int m  = blockIdx.x >> 9;

    if (tid < 64) {                        // stage h_last[b, es*32 .. +32)
        int b = tid >> 3, e4 = tid & 7;
        const vfloat4* src = reinterpret_cast<const vfloat4*>(
            hidden + (size_t)b * (SEQ * DIM) + (size_t)(SEQ - 1) * DIM + es * 32);
        reinterpret_cast<vfloat4*>(h_s[b])[e4] = src[e4];
    }
    __syncthreads();

    const int d4 = tid & 15;               // float4 of d within chunk
    const int eg = tid >> 4;               // 16 e-groups of 2
    const float* wbase = c_attn_w + (size_t)m * DIM * (2 * DIM) + DIM + c * 64 + d4 * 4;

    vfloat4 acc[BATCH];
#pragma unroll
    for (int b = 0; b < BATCH; ++b) acc[b] = (vfloat4){0.f, 0.f, 0.f, 0.f};

#pragma unroll
    for (int k = 0; k < 2; ++k) {
        int el = eg * 2 + k;               // 0..31
        int e  = es * 32 + el;
        vfloat4 w4 = __builtin_nontemporal_load(
            reinterpret_cast<const vfloat4*>(wbase + (size_t)e * (2 * DIM)));
#pragma unroll
        for (int b = 0; b < BATCH; ++b) acc[b] += h_s[b][el] * w4;
    }
#pragma unroll
    for (int b = 0; b < BATCH; ++b) vred[eg][d4][b] = acc[b];
    __syncthreads();

    if (tid < 128) {                       // reduce 16 e-groups
        int b = tid >> 4, dq = tid & 15;
        vfloat4 s = vred[0][dq][b];
#pragma unroll
        for (int g = 1; g < 16; ++g) s += vred[g][dq][b];
        reinterpret_cast<vfloat4*>(vp)[es * 4096 + (m * BATCH + b) * 256 + c * 16 + dq] = s;
    }
}

// ---------- Kernel B: yp tiles (R6 shape, 32 vp partials) ----------
// grid 512 = m(2) x cd(16) x ce(16); 256 thr.  Wp tile read ONCE (nontemporal).
__global__ void __launch_bounds__(256) kernelB(const float* __restrict__ vp,
                                               const float* __restrict__ c_attn_b,
                                               const float* __restrict__ c_proj_w,
                                               float* __restrict__ yp) {
    __shared__ float v_s[BATCH][64];
    __shared__ vfloat4 yred[16][16][9];    // [dg][e4][b] (padded)

    const int tid = threadIdx.x;
    const int ce = blockIdx.x & 15;
    const int cd = (blockIdx.x >> 4) & 15;
    const int m  = blockIdx.x >> 8;

    if (tid < 128) {                       // v_s[b][dl] = bias + 32 partials
        int b = tid >> 4, d4 = tid & 15;
        vfloat4 s = reinterpret_cast<const vfloat4*>(
            c_attn_b + (size_t)m * 2 * DIM + DIM)[cd * 16 + d4];
        const vfloat4* vp4 = reinterpret_cast<const vfloat4*>(vp);
#pragma unroll
        for (int es = 0; es < 32; ++es) {
            s += vp4[es * 4096 + (m * BATCH + b) * 256 + cd * 16 + d4];
        }
        reinterpret_cast<vfloat4*>(v_s[b])[d4] = s;
    }
    __syncthreads();

    const int e4 = tid & 15;               // float4 of e within 64-e range
    const int dg = tid >> 4;               // 16 d-groups of 4
    const float* wbase = c_proj_w + (size_t)m * DIM * DIM + ce * 64 + e4 * 4;

    vfloat4 acc[BATCH];
#pragma unroll
    for (int b = 0; b < BATCH; ++b) acc[b] = (vfloat4){0.f, 0.f, 0.f, 0.f};

#pragma unroll
    for (int j = 0; j < 4; ++j) {
        int dl = dg * 4 + j;               // 0..63
        int d  = cd * 64 + dl;
        vfloat4 w4 = __builtin_nontemporal_load(
            reinterpret_cast<const vfloat4*>(wbase + (size_t)d * DIM));
#pragma unroll
        for (int b = 0; b < BATCH; ++b) acc[b] += v_s[b][dl] * w4;
    }
#pragma unroll
    for (int b = 0; b < BATCH; ++b) yred[dg][e4][b] = acc[b];
    __syncthreads();

    if (tid < 128) {                       // reduce 16 d-groups -> yp
        int b = tid >> 4, eq = tid & 15;
        vfloat4 s = yred[0][eq][b];
#pragma unroll
        for (int g = 1; g < 16; ++g) s += yred[g][eq][b];
        reinterpret_cast<vfloat4*>(yp)[cd * 4096 + (m * BATCH + b) * 256 + ce * 16 + eq] = s;
    }
}

// ---------- Kernel C: reduce yp + bias, broadcast store ----------
// 4096 blocks: b = bid>>9, q0 = (bid&511)*8; 8 contiguous q-rows per block.
__global__ void __launch_bounds__(256) bcast_reduce(const float* __restrict__ yp,
                                                    const float* __restrict__ c_proj_b,
                                                    float* __restrict__ out) {
    int b = blockIdx.x >> 9;
    int q0 = (blockIdx.x & 511) * 8;
    int t = threadIdx.x;                    // e4 = t (256 float4 = 1024 e)

    const vfloat4* bias4 = reinterpret_cast<const vfloat4*>(c_proj_b);
    const vfloat4* yp4 = reinterpret_cast<const vfloat4*>(yp);
    vfloat4 val = bias4[t];
#pragma unroll
    for (int cd = 0; cd < 16; ++cd) {
        val += yp4[cd * 4096 + b * 256 + t];
    }
    if (b == 0) {
        val += bias4[256 + t];
#pragma unroll
        for (int cd = 0; cd < 16; ++cd) {
            val += yp4[cd * 4096 + BATCH * 256 + t];
        }
    }

    vfloat4* o = reinterpret_cast<vfloat4*>(out) + ((size_t)b * QLEN + q0) * 256 + t;
#pragma unroll
    for (int q = 0; q < 8; ++q) {
        __builtin_nontemporal_store(val, o + (size_t)q * 256);
    }
}

extern "C" void kernel_launch(void* const* d_in, const int* in_sizes, int n_in,
                              void* d_out, int out_size, void* d_ws, size_t ws_size,
                              hipStream_t stream) {
    // inputs: encoder_hidden_states, hidden_states, q_w, q_b,
    //         c_attn_w, c_attn_b, c_proj_w, c_proj_b
    const float* hidden   = (const float*)d_in[1];
    const float* c_attn_w = (const float*)d_in[4];
    const float* c_attn_b = (const float*)d_in[5];
    const float* c_proj_w = (const float*)d_in[6];
    const float* c_proj_b = (const float*)d_in[7];
    float* out = (float*)d_out;

    float* vp = (float*)d_ws;               // 32*16384 f32 = 2 MB
    float* yp = vp + 32 * 16384;             // 16*16384 f32 = 1 MB

    kernelA<<<1024, 256, 0, stream>>>(hidden, c_attn_w, vp);
    kernelB<<<512, 256, 0, stream>>>(vp, c_attn_b, c_proj_w, yp);
    bcast_reduce<<<4096, 256, 0, stream>>>(yp, c_proj_b, out);
}